// Round 2
// baseline (494.808 us; speedup 1.0000x reference)
//
#include <hip/hip_runtime.h>
#include <hip/hip_bf16.h>
#include <stdint.h>

// Problem constants
#define TT    4096   // tokens
#define DD    1024   // input dim
#define HH    2048   // hidden
#define TWOH  4096
#define EE    8      // experts
#define NPAIR 8192   // T*K

typedef __attribute__((ext_vector_type(8))) short bf16x8;
typedef __attribute__((ext_vector_type(4))) float f32x4;

__device__ __forceinline__ unsigned short f32_bf16(float f) {
  union { float f; unsigned int u; } v; v.f = f;
  return (unsigned short)((v.u + 0x7FFFu + ((v.u >> 16) & 1u)) >> 16);
}

__device__ __forceinline__ void gload_lds16(const unsigned short* g, unsigned short* l) {
  __builtin_amdgcn_global_load_lds(
      (const __attribute__((address_space(1))) unsigned int*)g,
      (__attribute__((address_space(3))) unsigned int*)l, 16, 0, 0);
}

// ---------------- convert x (fp32 -> bf16) ----------------
__global__ void k_convert_x(const float* __restrict__ x, unsigned short* __restrict__ xb) {
  int i = blockIdx.x * blockDim.x + threadIdx.x;  // over float4 groups
  const float4* x4 = (const float4*)x;
  float4 v = x4[i];
  ushort4 o;
  o.x = f32_bf16(v.x); o.y = f32_bf16(v.y); o.z = f32_bf16(v.z); o.w = f32_bf16(v.w);
  *(ushort4*)(xb + (size_t)i * 4) = o;
}

// ------------- transpose-convert [R][C] f32 -> [C][R] bf16, per expert (z) -------------
__global__ void k_transpose_bf16(const float* __restrict__ src, unsigned short* __restrict__ dst,
                                 int R, int C) {
  __shared__ float tile[32][33];
  int e = blockIdx.z;
  const float* s = src + (size_t)e * R * C;
  unsigned short* d = dst + (size_t)e * R * C;
  int c0 = blockIdx.x * 32, r0 = blockIdx.y * 32;
  int tx = threadIdx.x, ty = threadIdx.y;
#pragma unroll
  for (int i = 0; i < 32; i += 8)
    tile[ty + i][tx] = s[(size_t)(r0 + ty + i) * C + c0 + tx];
  __syncthreads();
#pragma unroll
  for (int i = 0; i < 32; i += 8)
    d[(size_t)(c0 + ty + i) * R + r0 + tx] = f32_bf16(tile[tx][ty + i]);
}

// ---------------- router: counting sort of (t,k) pairs by expert ----------------
__global__ void k_route(const int* __restrict__ idx, const float* __restrict__ p,
                        int* __restrict__ tok, float* __restrict__ pw, int* __restrict__ se) {
  __shared__ int cnt[EE];
  __shared__ int base[EE];
  __shared__ int cur[EE];
  int t = threadIdx.x;
  if (t < EE) cnt[t] = 0;
  __syncthreads();
  for (int i = t; i < NPAIR; i += blockDim.x) atomicAdd(&cnt[idx[i]], 1);
  __syncthreads();
  if (t == 0) {
    int acc = 0;
    for (int e = 0; e < EE; e++) { base[e] = acc; cur[e] = acc; acc += cnt[e]; }
  }
  __syncthreads();
  for (int i = t; i < NPAIR; i += blockDim.x) {
    int e = idx[i];
    int pos = atomicAdd(&cur[e], 1);
    tok[pos] = i >> 1;   // token id (K=2)
    pw[pos]  = p[i];
  }
  if (t < EE) { se[t] = base[t]; se[EE + t] = base[t] + cnt[t]; }
}

// ---------------- GEMM1: act = GLU(x_rows @ W_up[e]), fused h/gates ----------------
// A: gathered xb rows [M][K=1024]; B: wup_bt [E][2H][D] ([N][K]); out: act bf16 [pos][H]
// tile: 128 rows x 64 act-cols (=> 128 up-cols), BK=64, 4 waves (2x2), 16x16x32 MFMA
__launch_bounds__(256)
__global__ void k_gemm1(const unsigned short* __restrict__ xb,
                        const unsigned short* __restrict__ wup,  // [E][2H][D]
                        const int* __restrict__ tok,
                        const int* __restrict__ se,
                        unsigned short* __restrict__ act) {
  const int e = blockIdx.z;
  const int start = se[e], end = se[EE + e];
  const int row_base = start + blockIdx.y * 128;
  if (row_base >= end) return;
  const int c0 = blockIdx.x * 64;  // act column base

  __shared__ __align__(16) unsigned short Als[128 * 64];
  __shared__ __align__(16) unsigned short Bls[128 * 64];

  const int t = threadIdx.x;
  const int lane = t & 63;
  const int w = t >> 6;
  const int wr = w >> 1, wc = w & 1;

  // staging precompute: thread t handles 4 issues; row = i*32 + t/8, slot swizzled
  const int srow = t >> 3;                  // 0..31
  const int ls = (t & 7) ^ (srow & 7);      // logical 16B slot (pre-swizzled source)
  const unsigned short* wup_e = wup + (size_t)e * TWOH * DD;

  const unsigned short* srcA[4];
  const unsigned short* srcB[4];
  unsigned short* dstA[4];
  unsigned short* dstB[4];
#pragma unroll
  for (int i = 0; i < 4; i++) {
    int row = i * 32 + srow;
    int ridx = row_base + row; if (ridx > end - 1) ridx = end - 1;   // clamp padding rows
    srcA[i] = xb + (size_t)tok[ridx] * DD + ls * 8;
    int nrow = (row < 64) ? (c0 + row) : (HH + c0 + (row - 64));     // h-half | gates-half
    srcB[i] = wup_e + (size_t)nrow * DD + ls * 8;
    dstA[i] = Als + ((size_t)i * 256 + t) * 8;
    dstB[i] = Bls + ((size_t)i * 256 + t) * 8;
  }

  f32x4 acc_h[4][2], acc_g[4][2];
#pragma unroll
  for (int m = 0; m < 4; m++)
#pragma unroll
    for (int n = 0; n < 2; n++) {
      acc_h[m][n] = (f32x4){0.f, 0.f, 0.f, 0.f};
      acc_g[m][n] = (f32x4){0.f, 0.f, 0.f, 0.f};
    }

  for (int kt = 0; kt < DD / 64; kt++) {
#pragma unroll
    for (int i = 0; i < 4; i++) gload_lds16(srcA[i], dstA[i]);
#pragma unroll
    for (int i = 0; i < 4; i++) gload_lds16(srcB[i], dstB[i]);
#pragma unroll
    for (int i = 0; i < 4; i++) { srcA[i] += 64; srcB[i] += 64; }
    __syncthreads();   // compiler drains vmcnt before barrier

#pragma unroll
    for (int ksub = 0; ksub < 2; ksub++) {
      const int kslot = ksub * 4 + (lane >> 4);
      bf16x8 a[4], bh[2], bg[2];
#pragma unroll
      for (int m = 0; m < 4; m++) {
        int r = wr * 64 + m * 16 + (lane & 15);
        a[m] = *(const bf16x8*)(Als + r * 64 + ((kslot ^ (r & 7)) * 8));
      }
#pragma unroll
      for (int n = 0; n < 2; n++) {
        int rh = wc * 32 + n * 16 + (lane & 15);
        bh[n] = *(const bf16x8*)(Bls + rh * 64 + ((kslot ^ (rh & 7)) * 8));
        int rg = 64 + rh;
        bg[n] = *(const bf16x8*)(Bls + rg * 64 + ((kslot ^ (rg & 7)) * 8));
      }
#pragma unroll
      for (int m = 0; m < 4; m++)
#pragma unroll
        for (int n = 0; n < 2; n++) {
          acc_h[m][n] = __builtin_amdgcn_mfma_f32_16x16x32_bf16(a[m], bh[n], acc_h[m][n], 0, 0, 0);
          acc_g[m][n] = __builtin_amdgcn_mfma_f32_16x16x32_bf16(a[m], bg[n], acc_g[m][n], 0, 0, 0);
        }
    }
    __syncthreads();
  }

  // epilogue: GLU + bf16 store.  C/D layout: col=lane&15, row=(lane>>4)*4+reg
#pragma unroll
  for (int m = 0; m < 4; m++) {
#pragma unroll
    for (int j = 0; j < 4; j++) {
      int rloc = wr * 64 + m * 16 + ((lane >> 4) * 4) + j;
      int rg = row_base + rloc;
      if (rg < end) {
#pragma unroll
        for (int n = 0; n < 2; n++) {
          float h = acc_h[m][n][j];
          float g = acc_g[m][n][j];
          float sv = (g / (1.f + __expf(-g))) * h;   // silu(g) * h
          act[(size_t)rg * HH + (c0 + wc * 32 + n * 16 + (lane & 15))] = f32_bf16(sv);
        }
      }
    }
  }
}

// ---------------- GEMM2: y[tok] += p * (act_rows @ W_down[e]) ----------------
// A: act [pos][K=2048]; B: wdn_bt [E][D][H] ([N][K]); tile 128x128, 4 waves (2x2)
__launch_bounds__(256)
__global__ void k_gemm2(const unsigned short* __restrict__ act,
                        const unsigned short* __restrict__ wdn,  // [E][D][H]
                        const int* __restrict__ tok,
                        const float* __restrict__ pw,
                        const int* __restrict__ se,
                        float* __restrict__ y) {
  const int e = blockIdx.z;
  const int start = se[e], end = se[EE + e];
  const int row_base = start + blockIdx.y * 128;
  if (row_base >= end) return;
  const int c0 = blockIdx.x * 128;  // output (D) column base

  __shared__ __align__(16) unsigned short Als[128 * 64];
  __shared__ __align__(16) unsigned short Bls[128 * 64];

  const int t = threadIdx.x;
  const int lane = t & 63;
  const int w = t >> 6;
  const int wr = w >> 1, wc = w & 1;

  const int srow = t >> 3;
  const int ls = (t & 7) ^ (srow & 7);
  const unsigned short* wdn_e = wdn + (size_t)e * DD * HH;

  const unsigned short* srcA[4];
  const unsigned short* srcB[4];
  unsigned short* dstA[4];
  unsigned short* dstB[4];
#pragma unroll
  for (int i = 0; i < 4; i++) {
    int row = i * 32 + srow;
    int ridx = row_base + row; if (ridx > end - 1) ridx = end - 1;
    srcA[i] = act + (size_t)ridx * HH + ls * 8;
    srcB[i] = wdn_e + (size_t)(c0 + row) * HH + ls * 8;
    dstA[i] = Als + ((size_t)i * 256 + t) * 8;
    dstB[i] = Bls + ((size_t)i * 256 + t) * 8;
  }

  f32x4 acc[4][4];
#pragma unroll
  for (int m = 0; m < 4; m++)
#pragma unroll
    for (int n = 0; n < 4; n++) acc[m][n] = (f32x4){0.f, 0.f, 0.f, 0.f};

  for (int kt = 0; kt < HH / 64; kt++) {
#pragma unroll
    for (int i = 0; i < 4; i++) gload_lds16(srcA[i], dstA[i]);
#pragma unroll
    for (int i = 0; i < 4; i++) gload_lds16(srcB[i], dstB[i]);
#pragma unroll
    for (int i = 0; i < 4; i++) { srcA[i] += 64; srcB[i] += 64; }
    __syncthreads();

#pragma unroll
    for (int ksub = 0; ksub < 2; ksub++) {
      const int kslot = ksub * 4 + (lane >> 4);
      bf16x8 a[4], b[4];
#pragma unroll
      for (int m = 0; m < 4; m++) {
        int r = wr * 64 + m * 16 + (lane & 15);
        a[m] = *(const bf16x8*)(Als + r * 64 + ((kslot ^ (r & 7)) * 8));
      }
#pragma unroll
      for (int n = 0; n < 4; n++) {
        int rb = wc * 64 + n * 16 + (lane & 15);
        b[n] = *(const bf16x8*)(Bls + rb * 64 + ((kslot ^ (rb & 7)) * 8));
      }
#pragma unroll
      for (int m = 0; m < 4; m++)
#pragma unroll
        for (int n = 0; n < 4; n++)
          acc[m][n] = __builtin_amdgcn_mfma_f32_16x16x32_bf16(a[m], b[n], acc[m][n], 0, 0, 0);
    }
    __syncthreads();
  }

  // epilogue: scale by gate prob, atomic-accumulate into y
#pragma unroll
  for (int m = 0; m < 4; m++) {
#pragma unroll
    for (int j = 0; j < 4; j++) {
      int rloc = wr * 64 + m * 16 + ((lane >> 4) * 4) + j;
      int rg = row_base + rloc;
      if (rg < end) {
        int tk = tok[rg];
        float p = pw[rg];
#pragma unroll
        for (int n = 0; n < 4; n++) {
          int col = c0 + wc * 64 + n * 16 + (lane & 15);
          atomicAdd(&y[(size_t)tk * DD + col], p * acc[m][n][j]);
        }
      }
    }
  }
}

// ---------------- launch ----------------
extern "C" void kernel_launch(void* const* d_in, const int* in_sizes, int n_in,
                              void* d_out, int out_size, void* d_ws, size_t ws_size,
                              hipStream_t stream) {
  const float* x        = (const float*)d_in[0];
  const float* expert_p = (const float*)d_in[1];
  const int*   expert_i = (const int*)d_in[2];
  const float* W_up     = (const float*)d_in[3];
  const float* W_down   = (const float*)d_in[4];
  float* y = (float*)d_out;

  char* ws = (char*)d_ws;
  // workspace layout (bytes)
  const size_t OFF_XB  = 0;                       // [T][D] bf16        8.4 MB
  const size_t OFF_WUP = 8388608;                 // [E][2H][D] bf16   67.1 MB
  const size_t OFF_WDN = 75497472;                // [E][D][H] bf16    33.6 MB
  const size_t OFF_ACT = 109051904;               // [NPAIR][H] bf16   33.6 MB
  const size_t OFF_TOK = 142606336;               // [NPAIR] int
  const size_t OFF_PW  = 142639104;               // [NPAIR] float
  const size_t OFF_SE  = 142671872;               // start[8], end[8]

  unsigned short* xb   = (unsigned short*)(ws + OFF_XB);
  unsigned short* wupb = (unsigned short*)(ws + OFF_WUP);
  unsigned short* wdnb = (unsigned short*)(ws + OFF_WDN);
  unsigned short* actb = (unsigned short*)(ws + OFF_ACT);
  int*   tok = (int*)(ws + OFF_TOK);
  float* pw  = (float*)(ws + OFF_PW);
  int*   se  = (int*)(ws + OFF_SE);

  // 1. convert x to bf16
  k_convert_x<<<(TT * DD / 4 + 255) / 256, 256, 0, stream>>>(x, xb);
  // 2. transpose-convert weights: W_up [E][D][2H] -> [E][2H][D]; W_down [E][H][D] -> [E][D][H]
  k_transpose_bf16<<<dim3(TWOH / 32, DD / 32, EE), dim3(32, 8), 0, stream>>>(W_up, wupb, DD, TWOH);
  k_transpose_bf16<<<dim3(DD / 32, HH / 32, EE), dim3(32, 8), 0, stream>>>(W_down, wdnb, HH, DD);
  // 3. route (counting sort by expert)
  k_route<<<1, 1024, 0, stream>>>(expert_i, expert_p, tok, pw, se);
  // 4. up-proj + GLU
  k_gemm1<<<dim3(HH / 64, NPAIR / 128, EE), 256, 0, stream>>>(xb, wupb, tok, se, actb);
  // 5. zero output, then down-proj with atomic combine
  hipMemsetAsync(d_out, 0, (size_t)TT * DD * sizeof(float), stream);
  k_gemm2<<<dim3(DD / 128, NPAIR / 128, EE), 256, 0, stream>>>(actb, wdnb, tok, pw, se, y);
}

// Round 5
// 471.577 us; speedup vs baseline: 1.0493x; 1.0493x over previous
//
#include <hip/hip_runtime.h>
#include <hip/hip_bf16.h>
#include <stdint.h>

// Problem constants
#define TT    4096   // tokens
#define DD    1024   // input dim
#define HH    2048   // hidden
#define TWOH  4096
#define EE    8      // experts
#define NPAIR 8192   // T*K

typedef __attribute__((ext_vector_type(8))) short bf16x8;
typedef __attribute__((ext_vector_type(4))) float f32x4;

__device__ __forceinline__ unsigned short f32_bf16(float f) {
  union { float f; unsigned int u; } v; v.f = f;
  return (unsigned short)((v.u + 0x7FFFu + ((v.u >> 16) & 1u)) >> 16);
}

__device__ __forceinline__ void gload_lds16(const unsigned short* g, unsigned short* l) {
  __builtin_amdgcn_global_load_lds(
      (const __attribute__((address_space(1))) unsigned int*)g,
      (__attribute__((address_space(3))) unsigned int*)l, 16, 0, 0);
}

// ---------------- convert x (fp32 -> bf16) ----------------
__global__ void k_convert_x(const float* __restrict__ x, unsigned short* __restrict__ xb) {
  int i = blockIdx.x * blockDim.x + threadIdx.x;  // over float4 groups
  const float4* x4 = (const float4*)x;
  float4 v = x4[i];
  ushort4 o;
  o.x = f32_bf16(v.x); o.y = f32_bf16(v.y); o.z = f32_bf16(v.z); o.w = f32_bf16(v.w);
  *(ushort4*)(xb + (size_t)i * 4) = o;
}

// ------------- transpose-convert [R][C] f32 -> [C][R] bf16, per expert (z) -------------
// 64x64 tile per 256-thread block. float4 loads (16B/lane), ushort4 stores (8B/lane).
// LDS [64][65]: both phases <=2-way bank aliasing (free).
__global__ void k_transpose64(const float* __restrict__ src, unsigned short* __restrict__ dst,
                              int R, int C) {
  __shared__ float tile[64][65];
  int e = blockIdx.z;
  const float* s = src + (size_t)e * R * C;
  unsigned short* d = dst + (size_t)e * R * C;
  int c0 = blockIdx.x * 64, r0 = blockIdx.y * 64;
  int t = threadIdx.x;
  int lr = t >> 4;            // 0..15
  int lc = (t & 15) * 4;      // 0,4,...,60
#pragma unroll
  for (int i = 0; i < 4; i++) {
    int r = i * 16 + lr;
    float4 v = *(const float4*)(s + (size_t)(r0 + r) * C + c0 + lc);
    tile[r][lc + 0] = v.x; tile[r][lc + 1] = v.y;
    tile[r][lc + 2] = v.z; tile[r][lc + 3] = v.w;
  }
  __syncthreads();
  int sc = t >> 4;            // out-row (c) sub-index
  int sr = (t & 15) * 4;      // out-col (r) base
#pragma unroll
  for (int i = 0; i < 4; i++) {
    int c = i * 16 + sc;
    ushort4 o;
    o.x = f32_bf16(tile[sr + 0][c]);
    o.y = f32_bf16(tile[sr + 1][c]);
    o.z = f32_bf16(tile[sr + 2][c]);
    o.w = f32_bf16(tile[sr + 3][c]);
    *(ushort4*)(d + (size_t)(c0 + c) * R + r0 + sr) = o;
  }
}

// ---------------- router: counting sort of (t,k) pairs by expert ----------------
// also records inverse permutation inv[pair] = sorted position (for the combine pass)
__global__ void k_route(const int* __restrict__ idx, const float* __restrict__ p,
                        int* __restrict__ tok, float* __restrict__ pw,
                        int* __restrict__ inv, int* __restrict__ se) {
  __shared__ int cnt[EE];
  __shared__ int base[EE];
  __shared__ int cur[EE];
  int t = threadIdx.x;
  if (t < EE) cnt[t] = 0;
  __syncthreads();
  for (int i = t; i < NPAIR; i += blockDim.x) atomicAdd(&cnt[idx[i]], 1);
  __syncthreads();
  if (t == 0) {
    int acc = 0;
    for (int e = 0; e < EE; e++) { base[e] = acc; cur[e] = acc; acc += cnt[e]; }
  }
  __syncthreads();
  for (int i = t; i < NPAIR; i += blockDim.x) {
    int e = idx[i];
    int pos = atomicAdd(&cur[e], 1);
    tok[pos] = i >> 1;   // token id (K=2)
    pw[pos]  = p[i];
    inv[i]   = pos;
  }
  if (t < EE) { se[t] = base[t]; se[EE + t] = base[t] + cnt[t]; }
}

// ---------------- GEMM1: act = GLU(x_rows @ W_up[e]), fused h/gates ----------------
// A: gathered xb rows [M][K=1024]; B: wup_bt [E][2H][D] ([N][K]); out: act bf16 [pos][H]
// tile: 128 rows x 64 act-cols (=> 128 up-cols), BK=64, 4 waves (2x2), 16x16x32 MFMA
__launch_bounds__(256)
__global__ void k_gemm1(const unsigned short* __restrict__ xb,
                        const unsigned short* __restrict__ wup,  // [E][2H][D]
                        const int* __restrict__ tok,
                        const int* __restrict__ se,
                        unsigned short* __restrict__ act) {
  const int e = blockIdx.z;
  const int start = se[e], end = se[EE + e];
  const int row_base = start + blockIdx.y * 128;
  if (row_base >= end) return;
  const int c0 = blockIdx.x * 64;  // act column base

  __shared__ __align__(16) unsigned short Als[128 * 64];
  __shared__ __align__(16) unsigned short Bls[128 * 64];

  const int t = threadIdx.x;
  const int lane = t & 63;
  const int w = t >> 6;
  const int wr = w >> 1, wc = w & 1;

  // staging precompute: thread t handles 4 issues; row = i*32 + t/8, slot swizzled
  const int srow = t >> 3;                  // 0..31
  const int ls = (t & 7) ^ (srow & 7);      // logical 16B slot (pre-swizzled source)
  const unsigned short* wup_e = wup + (size_t)e * TWOH * DD;

  const unsigned short* srcA[4];
  const unsigned short* srcB[4];
  unsigned short* dstA[4];
  unsigned short* dstB[4];
#pragma unroll
  for (int i = 0; i < 4; i++) {
    int row = i * 32 + srow;
    int ridx = row_base + row; if (ridx > end - 1) ridx = end - 1;   // clamp padding rows
    srcA[i] = xb + (size_t)tok[ridx] * DD + ls * 8;
    int nrow = (row < 64) ? (c0 + row) : (HH + c0 + (row - 64));     // h-half | gates-half
    srcB[i] = wup_e + (size_t)nrow * DD + ls * 8;
    dstA[i] = Als + ((size_t)i * 256 + t) * 8;
    dstB[i] = Bls + ((size_t)i * 256 + t) * 8;
  }

  f32x4 acc_h[4][2], acc_g[4][2];
#pragma unroll
  for (int m = 0; m < 4; m++)
#pragma unroll
    for (int n = 0; n < 2; n++) {
      acc_h[m][n] = (f32x4){0.f, 0.f, 0.f, 0.f};
      acc_g[m][n] = (f32x4){0.f, 0.f, 0.f, 0.f};
    }

  for (int kt = 0; kt < DD / 64; kt++) {
#pragma unroll
    for (int i = 0; i < 4; i++) gload_lds16(srcA[i], dstA[i]);
#pragma unroll
    for (int i = 0; i < 4; i++) gload_lds16(srcB[i], dstB[i]);
#pragma unroll
    for (int i = 0; i < 4; i++) { srcA[i] += 64; srcB[i] += 64; }
    __syncthreads();   // compiler drains vmcnt before barrier

#pragma unroll
    for (int ksub = 0; ksub < 2; ksub++) {
      const int kslot = ksub * 4 + (lane >> 4);
      bf16x8 a[4], bh[2], bg[2];
#pragma unroll
      for (int m = 0; m < 4; m++) {
        int r = wr * 64 + m * 16 + (lane & 15);
        a[m] = *(const bf16x8*)(Als + r * 64 + ((kslot ^ (r & 7)) * 8));
      }
#pragma unroll
      for (int n = 0; n < 2; n++) {
        int rh = wc * 32 + n * 16 + (lane & 15);
        bh[n] = *(const bf16x8*)(Bls + rh * 64 + ((kslot ^ (rh & 7)) * 8));
        int rg = 64 + rh;
        bg[n] = *(const bf16x8*)(Bls + rg * 64 + ((kslot ^ (rg & 7)) * 8));
      }
#pragma unroll
      for (int m = 0; m < 4; m++)
#pragma unroll
        for (int n = 0; n < 2; n++) {
          acc_h[m][n] = __builtin_amdgcn_mfma_f32_16x16x32_bf16(a[m], bh[n], acc_h[m][n], 0, 0, 0);
          acc_g[m][n] = __builtin_amdgcn_mfma_f32_16x16x32_bf16(a[m], bg[n], acc_g[m][n], 0, 0, 0);
        }
    }
    __syncthreads();
  }

  // epilogue: GLU + bf16 store.  C/D layout: col=lane&15, row=(lane>>4)*4+reg
#pragma unroll
  for (int m = 0; m < 4; m++) {
#pragma unroll
    for (int j = 0; j < 4; j++) {
      int rloc = wr * 64 + m * 16 + ((lane >> 4) * 4) + j;
      int rg = row_base + rloc;
      if (rg < end) {
#pragma unroll
        for (int n = 0; n < 2; n++) {
          float h = acc_h[m][n][j];
          float g = acc_g[m][n][j];
          float sv = (g / (1.f + __expf(-g))) * h;   // silu(g) * h
          act[(size_t)rg * HH + (c0 + wc * 32 + n * 16 + (lane & 15))] = f32_bf16(sv);
        }
      }
    }
  }
}

// ---------------- GEMM2: yp[pos] = p * (act_rows @ W_down[e]) ----------------
// A: act [pos][K=2048]; B: wdn_bt [E][D][H] ([N][K]); tile 128x128, 4 waves (2x2)
__launch_bounds__(256)
__global__ void k_gemm2(const unsigned short* __restrict__ act,
                        const unsigned short* __restrict__ wdn,  // [E][D][H]
                        const float* __restrict__ pw,
                        const int* __restrict__ se,
                        float* __restrict__ yp) {
  const int e = blockIdx.z;
  const int start = se[e], end = se[EE + e];
  const int row_base = start + blockIdx.y * 128;
  if (row_base >= end) return;
  const int c0 = blockIdx.x * 128;  // output (D) column base

  __shared__ __align__(16) unsigned short Als[128 * 64];
  __shared__ __align__(16) unsigned short Bls[128 * 64];

  const int t = threadIdx.x;
  const int lane = t & 63;
  const int w = t >> 6;
  const int wr = w >> 1, wc = w & 1;

  const int srow = t >> 3;
  const int ls = (t & 7) ^ (srow & 7);
  const unsigned short* wdn_e = wdn + (size_t)e * DD * HH;

  const unsigned short* srcA[4];
  const unsigned short* srcB[4];
  unsigned short* dstA[4];
  unsigned short* dstB[4];
#pragma unroll
  for (int i = 0; i < 4; i++) {
    int row = i * 32 + srow;
    int ridx = row_base + row; if (ridx > end - 1) ridx = end - 1;
    srcA[i] = act + (size_t)ridx * HH + ls * 8;
    srcB[i] = wdn_e + (size_t)(c0 + row) * HH + ls * 8;
    dstA[i] = Als + ((size_t)i * 256 + t) * 8;
    dstB[i] = Bls + ((size_t)i * 256 + t) * 8;
  }

  f32x4 acc[4][4];
#pragma unroll
  for (int m = 0; m < 4; m++)
#pragma unroll
    for (int n = 0; n < 4; n++) acc[m][n] = (f32x4){0.f, 0.f, 0.f, 0.f};

  for (int kt = 0; kt < HH / 64; kt++) {
#pragma unroll
    for (int i = 0; i < 4; i++) gload_lds16(srcA[i], dstA[i]);
#pragma unroll
    for (int i = 0; i < 4; i++) gload_lds16(srcB[i], dstB[i]);
#pragma unroll
    for (int i = 0; i < 4; i++) { srcA[i] += 64; srcB[i] += 64; }
    __syncthreads();

#pragma unroll
    for (int ksub = 0; ksub < 2; ksub++) {
      const int kslot = ksub * 4 + (lane >> 4);
      bf16x8 a[4], b[4];
#pragma unroll
      for (int m = 0; m < 4; m++) {
        int r = wr * 64 + m * 16 + (lane & 15);
        a[m] = *(const bf16x8*)(Als + r * 64 + ((kslot ^ (r & 7)) * 8));
      }
#pragma unroll
      for (int n = 0; n < 4; n++) {
        int rb = wc * 64 + n * 16 + (lane & 15);
        b[n] = *(const bf16x8*)(Bls + rb * 64 + ((kslot ^ (rb & 7)) * 8));
      }
#pragma unroll
      for (int m = 0; m < 4; m++)
#pragma unroll
        for (int n = 0; n < 4; n++)
          acc[m][n] = __builtin_amdgcn_mfma_f32_16x16x32_bf16(a[m], b[n], acc[m][n], 0, 0, 0);
    }
    __syncthreads();
  }

  // epilogue: scale by gate prob, plain coalesced store to yp
#pragma unroll
  for (int m = 0; m < 4; m++) {
#pragma unroll
    for (int j = 0; j < 4; j++) {
      int rloc = wr * 64 + m * 16 + ((lane >> 4) * 4) + j;
      int rg = row_base + rloc;
      if (rg < end) {
        float p = pw[rg];
#pragma unroll
        for (int n = 0; n < 4; n++) {
          int col = c0 + wc * 64 + n * 16 + (lane & 15);
          yp[(size_t)rg * DD + col] = p * acc[m][n][j];
        }
      }
    }
  }
}

// ---------------- combine: y[t] = yp[inv[2t]] + yp[inv[2t+1]] ----------------
__global__ void k_combine(const float* __restrict__ yp, const int* __restrict__ inv,
                          float* __restrict__ y) {
  int i = blockIdx.x * blockDim.x + threadIdx.x;  // over float4 of y, T*D/4 total
  int tk = i >> 8;          // token (D/4 = 256 float4 per token)
  int d4 = i & 255;
  const float4* yp4 = (const float4*)yp;
  float4 a = yp4[(size_t)inv[2 * tk] * (DD / 4) + d4];
  float4 b = yp4[(size_t)inv[2 * tk + 1] * (DD / 4) + d4];
  float4 o = make_float4(a.x + b.x, a.y + b.y, a.z + b.z, a.w + b.w);
  ((float4*)y)[i] = o;
}

// ---------------- launch ----------------
extern "C" void kernel_launch(void* const* d_in, const int* in_sizes, int n_in,
                              void* d_out, int out_size, void* d_ws, size_t ws_size,
                              hipStream_t stream) {
  const float* x        = (const float*)d_in[0];
  const float* expert_p = (const float*)d_in[1];
  const int*   expert_i = (const int*)d_in[2];
  const float* W_up     = (const float*)d_in[3];
  const float* W_down   = (const float*)d_in[4];
  float* y = (float*)d_out;

  char* ws = (char*)d_ws;
  // workspace layout (bytes)
  const size_t OFF_XB  = 0;                       // [T][D] bf16        8.4 MB
  const size_t OFF_WUP = 8388608;                 // [E][2H][D] bf16   67.1 MB (reused as yp after gemm1)
  const size_t OFF_WDN = 75497472;                // [E][D][H] bf16    33.6 MB
  const size_t OFF_ACT = 109051904;               // [NPAIR][H] bf16   33.6 MB
  const size_t OFF_TOK = 142606336;               // [NPAIR] int
  const size_t OFF_PW  = 142639104;               // [NPAIR] float
  const size_t OFF_INV = 142671872;               // [NPAIR] int
  const size_t OFF_SE  = 142704640;               // start[8], end[8]

  unsigned short* xb   = (unsigned short*)(ws + OFF_XB);
  unsigned short* wupb = (unsigned short*)(ws + OFF_WUP);
  unsigned short* wdnb = (unsigned short*)(ws + OFF_WDN);
  unsigned short* actb = (unsigned short*)(ws + OFF_ACT);
  float* yp  = (float*)(ws + OFF_WUP);            // alias: W_up bf16 dead after gemm1 (33.5 MB < 67.1 MB)
  int*   tok = (int*)(ws + OFF_TOK);
  float* pw  = (float*)(ws + OFF_PW);
  int*   inv = (int*)(ws + OFF_INV);
  int*   se  = (int*)(ws + OFF_SE);

  // 1. convert x to bf16
  k_convert_x<<<(TT * DD / 4 + 255) / 256, 256, 0, stream>>>(x, xb);
  // 2. transpose-convert weights: W_up [E][D][2H] -> [E][2H][D]; W_down [E][H][D] -> [E][D][H]
  k_transpose64<<<dim3(TWOH / 64, DD / 64, EE), 256, 0, stream>>>(W_up, wupb, DD, TWOH);
  k_transpose64<<<dim3(DD / 64, HH / 64, EE), 256, 0, stream>>>(W_down, wdnb, HH, DD);
  // 3. route (counting sort by expert, with inverse permutation)
  k_route<<<1, 1024, 0, stream>>>(expert_i, expert_p, tok, pw, inv, se);
  // 4. up-proj + GLU
  k_gemm1<<<dim3(HH / 64, NPAIR / 128, EE), 256, 0, stream>>>(xb, wupb, tok, se, actb);
  // 5. down-proj to per-pair rows (overwrites dead W_up-bf16 region)
  k_gemm2<<<dim3(DD / 128, NPAIR / 128, EE), 256, 0, stream>>>(actb, wdnb, pw, se, yp);
  // 6. gather-combine the two expert contributions per token
  k_combine<<<(TT * DD / 4) / 256, 256, 0, stream>>>(yp, inv, y);
}